// Round 5
// baseline (232.955 us; speedup 1.0000x reference)
//
#include <hip/hip_runtime.h>
#include <cmath>

#define NB 256
#define NS 8192
#define NF 2048
#define NK 20

typedef _Float16 half8 __attribute__((ext_vector_type(8)));
typedef _Float16 half4 __attribute__((ext_vector_type(4)));
typedef float f32x4 __attribute__((ext_vector_type(4)));

__device__ __forceinline__ void async16(const void* g, void* l) {
  __builtin_amdgcn_global_load_lds(
      (const __attribute__((address_space(1))) unsigned int*)g,
      (__attribute__((address_space(3))) unsigned int*)l, 16, 0, 0);
}

__device__ __forceinline__ float waveSum(float v) {
#pragma unroll
  for (int off = 32; off > 0; off >>= 1) v += __shfl_xor(v, off, 64);
  return v;
}
__device__ __forceinline__ float waveMax(float v) {
#pragma unroll
  for (int off = 32; off > 0; off >>= 1) v = fmaxf(v, __shfl_xor(v, off, 64));
  return v;
}

// ============ K1: prep ============
// [0,8192): features row -> out (aligned f4 stores; momentum winner rows) + fh fp16
// [8192,8704): row stats -> mll, alpha_h
// [8704,9216): Pt transpose (16 cols/blk), RAW exp fp16  (LDS 16.6 KB)
// [9216,9472): normalize x -> xh fp16
// 9472: zero Wp + neighbor-weight rows + zero done-counter
__global__ __launch_bounds__(256, 1) void prep(
    const float4* __restrict__ f4, const float* __restrict__ in0,
    const float* __restrict__ logits0, const float* __restrict__ logits1,
    const int* __restrict__ targets, const int* __restrict__ neighbors,
    const float* __restrict__ ndist,
    float* __restrict__ outF, _Float16* __restrict__ fh,
    _Float16* __restrict__ Pt, _Float16* __restrict__ xh,
    _Float16* __restrict__ alpha_h, float* __restrict__ mll,
    _Float16* __restrict__ Wp, int* __restrict__ cnt) {
  __shared__ alignas(16) union {
    struct {
      float redA[4];
      float redB[4];
      unsigned long long wmask[4];
    } s;
    _Float16 Lt[16 * 520];  // 16640 B -> 8 blocks/CU
  } sm;
  int tid = threadIdx.x, blk = blockIdx.x;
  int wave = tid >> 6, lane = tid & 63;

  if (blk < NS) {
    // ---- features row ----
    int row = blk;
    const float4* fr = f4 + (size_t)row * (NF / 4);
    float4 v0 = fr[tid], v1 = fr[tid + 256];
    half4 h0, h1;
    h0[0] = (_Float16)v0.x; h0[1] = (_Float16)v0.y; h0[2] = (_Float16)v0.z; h0[3] = (_Float16)v0.w;
    h1[0] = (_Float16)v1.x; h1[1] = (_Float16)v1.y; h1[2] = (_Float16)v1.z; h1[3] = (_Float16)v1.w;
    ((half4*)(fh + (size_t)row * NF))[tid] = h0;
    ((half4*)(fh + (size_t)row * NF))[tid + 256] = h1;
    // winner = last b with targets[b]==row
    unsigned long long mk = __ballot(targets[tid] == row);
    if (lane == 0) sm.s.wmask[wave] = mk;
    __syncthreads();
    int u = -1;
#pragma unroll
    for (int w = 3; w >= 0; --w)
      if (u < 0 && sm.s.wmask[w])
        u = w * 64 + 63 - (int)__clzll(sm.s.wmask[w]);
    if (u >= 0) {  // block-uniform
      const float4* xr = (const float4*)(in0 + (size_t)u * NF);
      float4 a0 = xr[tid], a1 = xr[tid + 256];
      float ssx = a0.x * a0.x + a0.y * a0.y + a0.z * a0.z + a0.w * a0.w +
                  a1.x * a1.x + a1.y * a1.y + a1.z * a1.z + a1.w * a1.w;
      float w1 = waveSum(ssx);
      if (lane == 0) sm.s.redA[wave] = w1;
      __syncthreads();
      float totx = (sm.s.redA[0] + sm.s.redA[1]) + (sm.s.redA[2] + sm.s.redA[3]);
      float ix = 0.8f / fmaxf(sqrtf(totx), 1e-12f);
      v0 = make_float4(0.2f * v0.x + ix * a0.x, 0.2f * v0.y + ix * a0.y,
                       0.2f * v0.z + ix * a0.z, 0.2f * v0.w + ix * a0.w);
      v1 = make_float4(0.2f * v1.x + ix * a1.x, 0.2f * v1.y + ix * a1.y,
                       0.2f * v1.z + ix * a1.z, 0.2f * v1.w + ix * a1.w);
      float ss = v0.x * v0.x + v0.y * v0.y + v0.z * v0.z + v0.w * v0.w +
                 v1.x * v1.x + v1.y * v1.y + v1.z * v1.z + v1.w * v1.w;
      float w2 = waveSum(ss);
      if (lane == 0) sm.s.redB[wave] = w2;
      __syncthreads();
      float tot = (sm.s.redB[0] + sm.s.redB[1]) + (sm.s.redB[2] + sm.s.redB[3]);
      float inv = 1.0f / fmaxf(sqrtf(tot), 1e-12f);
      v0.x *= inv; v0.y *= inv; v0.z *= inv; v0.w *= inv;
      v1.x *= inv; v1.y *= inv; v1.z *= inv; v1.w *= inv;
    }
    // aligned stores: out element e of row is 16B-aligned iff e % 4 == 1
    float* o = outF + (size_t)row * NF;
    float n0x = __shfl_down(v0.x, 1, 64);
    float n1x = __shfl_down(v1.x, 1, 64);
    if (lane != 63) {
      *(float4*)(o + 4 * tid + 1) = make_float4(v0.y, v0.z, v0.w, n0x);
      *(float4*)(o + 1024 + 4 * tid + 1) = make_float4(v1.y, v1.z, v1.w, n1x);
    } else {
      o[4 * tid + 1] = v0.y; o[4 * tid + 2] = v0.z; o[4 * tid + 3] = v0.w;
      o[1024 + 4 * tid + 1] = v1.y; o[1024 + 4 * tid + 2] = v1.z; o[1024 + 4 * tid + 3] = v1.w;
    }
    if (lane == 0) { o[4 * tid] = v0.x; o[1024 + 4 * tid] = v1.x; }
  } else if (blk < NS + 512) {
    // ---- row stats ----
    int r = blk - NS;
    const float* src = (r < NB) ? logits0 : logits1;
    const float4* row = (const float4*)(src + (size_t)(r & (NB - 1)) * NS);
    float4 v[8];
    float mx = -1e30f;
#pragma unroll
    for (int i = 0; i < 8; ++i) {
      v[i] = row[tid + i * 256];
      mx = fmaxf(mx, fmaxf(fmaxf(v[i].x, v[i].y), fmaxf(v[i].z, v[i].w)));
    }
    float wv = waveMax(mx);
    if (lane == 0) sm.s.redA[wave] = wv;
    __syncthreads();
    float m = fmaxf(fmaxf(sm.s.redA[0], sm.s.redA[1]), fmaxf(sm.s.redA[2], sm.s.redA[3]));
    float se = 0.0f;
#pragma unroll
    for (int i = 0; i < 8; ++i)
      se += expf(v[i].x - m) + expf(v[i].y - m) + expf(v[i].z - m) + expf(v[i].w - m);
    float sw = waveSum(se);
    if (lane == 0) sm.s.redB[wave] = sw;
    __syncthreads();
    float l = (sm.s.redB[0] + sm.s.redB[1]) + (sm.s.redB[2] + sm.s.redB[3]);
    if (tid == 0) {
      mll[r] = m + logf(l);
      alpha_h[r] = (_Float16)(256.0f * expf(-m) / l);
    }
  } else if (blk < NS + 1024) {
    // ---- Pt transpose (16 cols, raw exp) ----
    int s0 = (blk - (NS + 512)) * 16;
#pragma unroll
    for (int g = 0; g < 8; ++g) {
      int pos = g * 256 + tid;          // 2048 float4 slots = 512 rows x 4
      int row = pos >> 2, c4 = pos & 3;
      const float* src = ((row < NB) ? logits0 + (size_t)row * NS
                                     : logits1 + (size_t)(row - NB) * NS) + s0 + c4 * 4;
      float4 v = *(const float4*)src;
      sm.Lt[(c4 * 4 + 0) * 520 + row] = (_Float16)expf(v.x);
      sm.Lt[(c4 * 4 + 1) * 520 + row] = (_Float16)expf(v.y);
      sm.Lt[(c4 * 4 + 2) * 520 + row] = (_Float16)expf(v.z);
      sm.Lt[(c4 * 4 + 3) * 520 + row] = (_Float16)expf(v.w);
    }
    __syncthreads();
    int srow = tid >> 4, seg = tid & 15;  // 16 rows x 16 segs of 32 halves
    _Float16* dst = Pt + (size_t)(s0 + srow) * 512 + seg * 32;
    const _Float16* lsrc = &sm.Lt[srow * 520 + seg * 32];
#pragma unroll
    for (int q = 0; q < 4; ++q)
      *(half8*)(dst + q * 8) = *(const half8*)(lsrc + q * 8);
  } else if (blk < NS + 1280) {
    // ---- normalize x -> xh ----
    int b = blk - (NS + 1024);
    const float4* row = (const float4*)(in0 + (size_t)b * NF);
    float4 v0 = row[tid], v1 = row[tid + 256];
    float ss = v0.x * v0.x + v0.y * v0.y + v0.z * v0.z + v0.w * v0.w +
               v1.x * v1.x + v1.y * v1.y + v1.z * v1.z + v1.w * v1.w;
    float w = waveSum(ss);
    if (lane == 0) sm.s.redA[wave] = w;
    __syncthreads();
    float tot = (sm.s.redA[0] + sm.s.redA[1]) + (sm.s.redA[2] + sm.s.redA[3]);
    float inv = 1.0f / fmaxf(sqrtf(tot), 1e-12f);
    half4 h0, h1;
    h0[0] = (_Float16)(v0.x * inv); h0[1] = (_Float16)(v0.y * inv);
    h0[2] = (_Float16)(v0.z * inv); h0[3] = (_Float16)(v0.w * inv);
    h1[0] = (_Float16)(v1.x * inv); h1[1] = (_Float16)(v1.y * inv);
    h1[2] = (_Float16)(v1.z * inv); h1[3] = (_Float16)(v1.w * inv);
    ((half4*)(xh + (size_t)b * NF))[tid] = h0;
    ((half4*)(xh + (size_t)b * NF))[tid + 256] = h1;
  } else {
    // ---- weight-matrix build + counter reset ----
    float4* W4 = (float4*)Wp;
    for (int i = tid; i < 512 * 512 * 2 / 16; i += 256) W4[i] = make_float4(0, 0, 0, 0);
    if (tid == 0) *cnt = 0;
    __syncthreads();
    int b = tid;
    float d[NK], e[NK];
    int n[NK];
    float s = 0.0f;
    int c2 = 0;
#pragma unroll
    for (int k = 0; k < NK; ++k) {
      d[k] = ndist[b * NK + k];
      n[k] = neighbors[b * NK + k];
      e[k] = expf(d[k] * (1.0f / 0.6f));
      s += e[k];
      c2 += (d[k] <= 2.0f) ? 1 : 0;
    }
    float invs = 1.0f / (2.0f * s);
    float invc = 1.0f / fmaxf((float)c2, 1.0f);
    _Float16* rkl = Wp + (size_t)b * 512;
    _Float16* rce = Wp + (size_t)(256 + b) * 512;
#pragma unroll
    for (int k = 0; k < NK; ++k) {
      bool first = true;
#pragma unroll
      for (int k2 = 0; k2 < NK; ++k2)
        if (k2 < k && n[k2] == n[k]) first = false;
      if (first) {
        float wsum = 0.0f, ksum = 0.0f;
#pragma unroll
        for (int k2 = 0; k2 < NK; ++k2)
          if (k2 >= k && n[k2] == n[k]) {
            wsum += e[k2] * invs;
            ksum += (d[k2] <= 2.0f) ? invc : 0.0f;
          }
        rkl[n[k]] = (_Float16)ksum;
        rce[n[k]] = (_Float16)wsum;
        rce[256 + n[k]] = (_Float16)wsum;
      }
    }
  }
}

// ============ K2: both GEMMs + fused last-block final reduce ============
__global__ __launch_bounds__(256) void gemms(
    const _Float16* __restrict__ xh, const _Float16* __restrict__ fh,
    const _Float16* __restrict__ Wp, const _Float16* __restrict__ Pt,
    const _Float16* __restrict__ alpha_h,
    const float* __restrict__ logits0, const float* __restrict__ logits1,
    const float* __restrict__ mll, const int* __restrict__ targets,
    const float* __restrict__ rampup,
    float* __restrict__ pm, float* __restrict__ pl, float* __restrict__ tgt,
    float* __restrict__ part, int* cnt, float* __restrict__ out) {
  __shared__ alignas(16) _Float16 As[128 * 64];
  __shared__ alignas(16) _Float16 Bs[128 * 64];
  __shared__ alignas(16) _Float16 Al[512];
  __shared__ float red[4];
  __shared__ int lastFlag;
  int tid = threadIdx.x, wave = tid >> 6, lane = tid & 63;
  int quad = lane >> 4, r16 = lane & 15, lrow = lane >> 3, lch = lane & 7;
  int blk = blockIdx.x;
  if (blk < 256) {
    int bx = blk & 127, by = blk >> 7;
    int n0 = bx * 64, m0 = by * 128;
    f32x4 acc[2][4] = {};
    for (int k0 = 0; k0 < NF; k0 += 64) {
      __syncthreads();
#pragma unroll
      for (int ss = 0; ss < 4; ++ss) {
        int rl = ss * 32 + wave * 8 + lrow;
        int sc = lch ^ (rl & 7);
        async16(xh + (size_t)(m0 + rl) * NF + k0 + sc * 8, &As[rl * 64 + lch * 8]);
      }
#pragma unroll
      for (int ss = 0; ss < 2; ++ss) {
        int rl = ss * 32 + wave * 8 + lrow;
        int sc = lch ^ (rl & 7);
        async16(fh + (size_t)(n0 + rl) * NF + k0 + sc * 8, &Bs[rl * 64 + lch * 8]);
      }
      __syncthreads();
#pragma unroll
      for (int sub = 0; sub < 2; ++sub) {
        int slot = ((sub * 4 + quad) ^ (r16 & 7)) * 8;
        half8 af[2], bf[4];
#pragma unroll
        for (int i = 0; i < 2; ++i)
          af[i] = *(const half8*)&As[(wave * 32 + i * 16 + r16) * 64 + slot];
#pragma unroll
        for (int j = 0; j < 4; ++j)
          bf[j] = *(const half8*)&Bs[(j * 16 + r16) * 64 + slot];
#pragma unroll
        for (int i = 0; i < 2; ++i)
#pragma unroll
          for (int j = 0; j < 4; ++j)
            acc[i][j] = __builtin_amdgcn_mfma_f32_16x16x32_f16(af[i], bf[j], acc[i][j], 0, 0, 0);
      }
    }
#pragma unroll
    for (int i = 0; i < 2; ++i)
#pragma unroll
      for (int r = 0; r < 4; ++r) {
        int R = m0 + wave * 32 + i * 16 + quad * 4 + r;
        float sv[4];
#pragma unroll
        for (int j = 0; j < 4; ++j) sv[j] = acc[i][j][r] * 20.0f;
        float mx = fmaxf(fmaxf(sv[0], sv[1]), fmaxf(sv[2], sv[3]));
#pragma unroll
        for (int m2 = 1; m2 < 16; m2 <<= 1) mx = fmaxf(mx, __shfl_xor(mx, m2, 64));
        float e = expf(sv[0] - mx) + expf(sv[1] - mx) + expf(sv[2] - mx) + expf(sv[3] - mx);
#pragma unroll
        for (int m2 = 1; m2 < 16; m2 <<= 1) e += __shfl_xor(e, m2, 64);
        int tg = targets[R];
#pragma unroll
        for (int j = 0; j < 4; ++j)
          if (n0 + j * 16 + r16 == tg) tgt[R] = sv[j];
        if (r16 == 0) { pm[R * 128 + bx] = mx; pl[R * 128 + bx] = e; }
      }
  } else {
    int nb = blk - 256;
    int bx = nb & 63, by = nb >> 6;
    int n0 = bx * 128, m0 = by * 128;
    int wm = (wave >> 1) * 64, wn = (wave & 1) * 64;
    if (tid < 64) ((half8*)Al)[tid] = ((const half8*)alpha_h)[tid];
    f32x4 acc[4][4] = {};
    for (int k0 = 0; k0 < 512; k0 += 64) {
      __syncthreads();
#pragma unroll
      for (int ss = 0; ss < 4; ++ss) {
        int rl = ss * 32 + wave * 8 + lrow;
        int sc = lch ^ (rl & 7);
        async16(Wp + (size_t)(m0 + rl) * 512 + k0 + sc * 8, &As[rl * 64 + lch * 8]);
        async16(Pt + (size_t)(n0 + rl) * 512 + k0 + sc * 8, &Bs[rl * 64 + lch * 8]);
      }
      __syncthreads();
#pragma unroll
      for (int sub = 0; sub < 2; ++sub) {
        int slot = ((sub * 4 + quad) ^ (r16 & 7)) * 8;
        half8 alv = *(const half8*)&Al[k0 + slot];
        half8 af[4], bf[4];
#pragma unroll
        for (int i = 0; i < 4; ++i)
          af[i] = *(const half8*)&As[(wm + i * 16 + r16) * 64 + slot];
#pragma unroll
        for (int j = 0; j < 4; ++j)
          bf[j] = *(const half8*)&Bs[(wn + j * 16 + r16) * 64 + slot] * alv;
#pragma unroll
        for (int i = 0; i < 4; ++i)
#pragma unroll
          for (int j = 0; j < 4; ++j)
            acc[i][j] = __builtin_amdgcn_mfma_f32_16x16x32_f16(af[i], bf[j], acc[i][j], 0, 0, 0);
      }
    }
    bool iskl = (by < 2);
    const float* lgbase = iskl ? logits1 : logits0;
    float local = 0.0f;
#pragma unroll
    for (int i = 0; i < 4; ++i)
#pragma unroll
      for (int r = 0; r < 4; ++r) {
        int Mg = m0 + wm + i * 16 + quad * 4 + r;
        int b = iskl ? Mg : (Mg - 256);
        float mv = mll[iskl ? 256 + b : b];
        const float* lgrow = lgbase + (size_t)b * NS + n0 + wn;
#pragma unroll
        for (int j = 0; j < 4; ++j) {
          float lg = lgrow[j * 16 + r16];
          float t = acc[i][j][r] * (1.0f / 256.0f);
          if (iskl)
            local += (t > 0.0f) ? t * (logf(fmaxf(t, 1e-12f)) - (lg - mv)) : 0.0f;
          else
            local += -0.1f * t * (lg - mv);
        }
      }
    float wsv = waveSum(local);
    if (lane == 0) red[wave] = wsv;
    __syncthreads();
    if (tid == 0) part[nb] = (red[0] + red[1]) + (red[2] + red[3]);
  }

  // ---- last-block fused final reduce ----
  __syncthreads();
  if (tid == 0) {
    int prev = __hip_atomic_fetch_add(cnt, 1, __ATOMIC_ACQ_REL, __HIP_MEMORY_SCOPE_AGENT);
    lastFlag = (prev == 511);
  }
  __syncthreads();
  if (!lastFlag) return;
  __threadfence();

  __shared__ float rA[4], rB[4], rC[4], rD[4];
  int b = tid;
  const float* pmb = pm + b * 128;
  const float* plb = pl + b * 128;
  float mx = -1e30f;
#pragma unroll 8
  for (int s = 0; s < 128; ++s) mx = fmaxf(mx, pmb[s]);
  float S = 0.0f;
#pragma unroll 8
  for (int s = 0; s < 128; ++s) S += plb[s] * expf(pmb[s] - mx);
  float nce = -(tgt[b] - mx - logf(S));
  int tg = targets[b];
  float oh = -0.9f * (logits0[(size_t)b * NS + tg] - mll[b]);
  float c = part[tid];
  float klc = (tid < 128) ? c : 0.0f;
  float cec = (tid < 128) ? 0.0f : c;
  float wn_ = waveSum(nce), wo = waveSum(oh), wk = waveSum(klc), wc = waveSum(cec);
  if (lane == 0) { rA[wave] = wn_; rB[wave] = wo; rC[wave] = wk; rD[wave] = wc; }
  __syncthreads();
  if (tid == 0) {
    float sn = rA[0] + rA[1] + rA[2] + rA[3];
    float so = rB[0] + rB[1] + rB[2] + rB[3];
    float sk = rC[0] + rC[1] + rC[2] + rC[3];
    float sc2 = rD[0] + rD[1] + rD[2] + rD[3];
    out[0] = sn * (1.0f / 256.0f);
    out[1] = (so + sc2) * (1.0f / 256.0f);
    out[2] = rampup[0] * sk * (1.0f / 256.0f);
  }
}

extern "C" void kernel_launch(void* const* d_in, const int* in_sizes, int n_in,
                              void* d_out, int out_size, void* d_ws, size_t ws_size,
                              hipStream_t stream) {
  const float* inputs0 = (const float*)d_in[0];
  const float* logits0 = (const float*)d_in[1];
  const float* logits1 = (const float*)d_in[2];
  const int* targets = (const int*)d_in[3];
  const int* neighbors = (const int*)d_in[5];
  const float* ndist = (const float*)d_in[6];
  const float* rampup = (const float*)d_in[7];
  const float* features = (const float*)d_in[8];
  float* out = (float*)d_out;

  char* ws = (char*)d_ws;
  float* mll = (float*)(ws + 4096);             // 2 KB
  _Float16* alpha_h = (_Float16*)(ws + 8192);   // 1 KB
  float* part = (float*)(ws + 12288);           // 1 KB
  float* tgt = (float*)(ws + 16384);            // 1 KB
  int* cnt = (int*)(ws + 20480);                // 4 B
  float* pm = (float*)(ws + 65536);             // 128 KB
  float* pl = (float*)(ws + 196608);            // 128 KB
  _Float16* Wp = (_Float16*)(ws + 524288);      // 512 KB
  _Float16* xh = (_Float16*)(ws + (3 << 20));   // 1 MB
  _Float16* Pt = (_Float16*)(ws + (4 << 20));   // 8 MB
  _Float16* fh = (_Float16*)(ws + (12 << 20));  // 32 MB

  prep<<<NS + 1281, 256, 0, stream>>>((const float4*)features, inputs0, logits0,
                                      logits1, targets, neighbors, ndist,
                                      out + 3, fh, Pt, xh, alpha_h, mll, Wp, cnt);
  gemms<<<512, 256, 0, stream>>>(xh, fh, Wp, Pt, alpha_h, logits0, logits1, mll,
                                 targets, rampup, pm, pl, tgt, part, cnt, out);
}